// Round 9
// baseline (154.672 us; speedup 1.0000x reference)
//
#include <hip/hip_runtime.h>
#include <math.h>

#define NN 512   // set size / rows of feat_x
#define IN 512   // INPUT_DIM
#define HD 256   // HIDDEN_DIM
#define RD 256   // REP_DIM
#define SH 128   // SCORE_HIDDEN

// Branchless erf-GELU, A&S 7.1.26 (5-term) -- g-MLP hidden layer.
__device__ __forceinline__ float gelu_fast(float x){
    const float z  = x * 0.70710678118654752f;
    const float az = fabsf(z);
    const float t  = __builtin_amdgcn_rcpf(fmaf(0.3275911f, az, 1.0f));
    float p = fmaf(1.061405429f, t, -1.453152027f);
    p = fmaf(p, t, 1.421413741f);
    p = fmaf(p, t, -0.284496736f);
    p = fmaf(p, t, 0.254829592f);
    p = p * t;
    const float e = __builtin_amdgcn_exp2f(z * z * -1.4426950408889634f);
    const float E = p * e;                        // erfc(|z|)
    const float one_plus_erf = (x >= 0.0f) ? (2.0f - E) : E;
    return 0.5f * x * one_plus_erf;
}

// K_REP: fused g-MLP + score-net projections + row norms (r15/r16 winner)
// + per-m score-linear partial pB[m] = Sum_k 0.5*s_w2[k]*B[k][m].
__global__ __launch_bounds__(512) void k_rep(
    const float* __restrict__ fx, const float* __restrict__ fp, const float* __restrict__ fn,
    const float* __restrict__ w1, const float* __restrict__ b1,
    const float* __restrict__ w2, const float* __restrict__ b2,
    const float* __restrict__ s_w1, const float* __restrict__ s_w2,
    float* __restrict__ r_x, float* __restrict__ r_p, float* __restrict__ r_n,
    float* __restrict__ rT_p, float* __restrict__ rT_n,
    float* __restrict__ A_x, float* __restrict__ BT_p, float* __restrict__ BT_n,
    float* __restrict__ nx2, float* __restrict__ np2, float* __restrict__ nn2,
    float* __restrict__ pB_p, float* __restrict__ pB_n)
{
    __shared__ float xs[4][IN];        // 8 KB
    __shared__ float ps[8][4][HD];     // 32 KB partials (reused by all GEMM phases)
    __shared__ float hs[4][HD];        // 4 KB
    __shared__ float rloc[4][RD];      // 4 KB
    __shared__ float ab4[4][SH];       // 2 KB
    const int t = threadIdx.x;
    const int mat = blockIdx.x >> 7;
    const int row0 = (blockIdx.x & 127) << 2;
    const float* src = (mat==0) ? fx : (mat==1) ? fp : fn;

    {   // stage 4 feat rows: 512 float4s
        const int j = t >> 7, c4 = (t & 127) << 2;
        *(float4*)&xs[j][c4] = *(const float4*)&src[(row0+j)*IN + c4];
    }
    __syncthreads();

    const int cg = t & 63, s = t >> 6;   // 64 colgroups x 8 K-slices
    const int c0 = cg << 2;

    {   // GEMM1: K=512, slice [s*64, s*64+64)
        float4 acc[4];
        #pragma unroll
        for (int j=0;j<4;j++) acc[j] = make_float4(0.f,0.f,0.f,0.f);
        const float* wp = w1 + (s*64)*HD + c0;
        #pragma unroll 8
        for (int ii=0; ii<64; ii++){
            float4 w = *(const float4*)wp; wp += HD;
            const int i = s*64 + ii;
            #pragma unroll
            for (int j=0;j<4;j++){
                const float xv = xs[j][i];
                acc[j].x = fmaf(xv, w.x, acc[j].x);
                acc[j].y = fmaf(xv, w.y, acc[j].y);
                acc[j].z = fmaf(xv, w.z, acc[j].z);
                acc[j].w = fmaf(xv, w.w, acc[j].w);
            }
        }
        #pragma unroll
        for (int j=0;j<4;j++) *(float4*)&ps[s][j][c0] = acc[j];
    }
    __syncthreads();

    #pragma unroll
    for (int rep=0; rep<2; rep++){   // reduce + bias + GELU -> hs
        const int idx = rep*512 + t;
        const int j = idx >> 8, c = idx & 255;
        float v = b1[c];
        #pragma unroll
        for (int ss=0; ss<8; ss++) v += ps[ss][j][c];
        hs[j][c] = gelu_fast(v);
    }
    __syncthreads();

    {   // GEMM2: K=256, slice [s*32, s*32+32)
        float4 acc[4];
        #pragma unroll
        for (int j=0;j<4;j++) acc[j] = make_float4(0.f,0.f,0.f,0.f);
        const float* wp = w2 + (s*32)*RD + c0;
        #pragma unroll 8
        for (int ii=0; ii<32; ii++){
            float4 w = *(const float4*)wp; wp += RD;
            const int i = s*32 + ii;
            #pragma unroll
            for (int j=0;j<4;j++){
                const float xv = hs[j][i];
                acc[j].x = fmaf(xv, w.x, acc[j].x);
                acc[j].y = fmaf(xv, w.y, acc[j].y);
                acc[j].z = fmaf(xv, w.z, acc[j].z);
                acc[j].w = fmaf(xv, w.w, acc[j].w);
            }
        }
        #pragma unroll
        for (int j=0;j<4;j++) *(float4*)&ps[s][j][c0] = acc[j];
    }
    __syncthreads();

    float* rout = (mat==0) ? r_x : (mat==1) ? r_p : r_n;
    #pragma unroll
    for (int rep=0; rep<2; rep++){   // reduce + bias -> rloc + global r
        const int idx = rep*512 + t;
        const int j = idx >> 8, c = idx & 255;
        float v = b2[c];
        #pragma unroll
        for (int ss=0; ss<8; ss++) v += ps[ss][j][c];
        rloc[j][c] = v;
        rout[(row0+j)*RD + c] = v;
    }
    __syncthreads();   // rloc complete; ps free for reuse

    if (t < 256){   // squared row norms: waves 0..3 -> rows 0..3
        const int w = t >> 6, l = t & 63;
        float v = 0.f;
        #pragma unroll
        for (int q=0;q<4;q++){ const float e = rloc[w][l + 64*q]; v = fmaf(e,e,v); }
        #pragma unroll
        for (int off=32; off>=1; off>>=1) v += __shfl_xor(v, off);
        if (l==0){
            float* nrm = (mat==0) ? nx2 : (mat==1) ? np2 : nn2;
            nrm[row0 + w] = v;
        }
    }
    if (mat && t < 256){   // transposed rep copy rT[r][m], float4 across rows
        float* rT = (mat==1) ? rT_p : rT_n;
        float4 q = make_float4(rloc[0][t], rloc[1][t], rloc[2][t], rloc[3][t]);
        *(float4*)&rT[t*NN + row0] = q;
    }

    {   // score-net projection: 128 cols, K=256 in 16 slices of 16
        const int cg2 = t & 31, s2 = t >> 5;
        const int cc0 = cg2 << 2;
        const float sgn = (mat==0) ? -1.0f : 1.0f;
        const int base1 = (mat==0) ? 0 : 256;
        const float* p1 = s_w1 + (base1 + s2*16)*SH + cc0;
        const float* p3 = s_w1 + (512   + s2*16)*SH + cc0;
        float4 a[4];
        #pragma unroll
        for (int j=0;j<4;j++) a[j] = make_float4(0.f,0.f,0.f,0.f);
        #pragma unroll 8
        for (int ii=0; ii<16; ii++){
            float4 wa = *(const float4*)p1; p1 += SH;
            float4 wd = *(const float4*)p3; p3 += SH;
            float4 w;
            w.x = fmaf(sgn, wd.x, wa.x);
            w.y = fmaf(sgn, wd.y, wa.y);
            w.z = fmaf(sgn, wd.z, wa.z);
            w.w = fmaf(sgn, wd.w, wa.w);
            const int i = s2*16 + ii;
            #pragma unroll
            for (int j=0;j<4;j++){
                const float xv = rloc[j][i];
                a[j].x = fmaf(xv, w.x, a[j].x);
                a[j].y = fmaf(xv, w.y, a[j].y);
                a[j].z = fmaf(xv, w.z, a[j].z);
                a[j].w = fmaf(xv, w.w, a[j].w);
            }
        }
        float* psf = &ps[0][0][0];   // reuse as [16][4][128]
        #pragma unroll
        for (int j=0;j<4;j++) *(float4*)&psf[(s2*4 + j)*SH + cc0] = a[j];
    }
    __syncthreads();

    {   // reduce 16 slices: 4 rows x 128 cols = 512 outputs
        const float* psf = &ps[0][0][0];
        const int j = t >> 7, c = t & 127;
        float v = 0.f;
        #pragma unroll
        for (int ss=0; ss<16; ss++) v += psf[(ss*4 + j)*SH + c];
        if (mat==0) A_x[(row0+j)*SH + c] = v;
        else        ab4[j][c] = v;
    }
    __syncthreads();
    if (mat && t < 128){   // BT[k][m], float4 across rows
        float* BT = (mat==1) ? BT_p : BT_n;
        float4 q = make_float4(ab4[0][t], ab4[1][t], ab4[2][t], ab4[3][t]);
        *(float4*)&BT[t*NN + row0] = q;
    }
    if (mat && t < 256){   // pB[m] = Sum_k (0.5*s_w2[k]) * B[k][m], wave w -> row w
        const int w = t >> 6, l = t & 63;
        const float w2a = 0.5f * s_w2[l];
        const float w2b = 0.5f * s_w2[l + 64];
        float v = ab4[w][l]*w2a + ab4[w][l+64]*w2b;
        #pragma unroll
        for (int off=32; off>=1; off>>=1) v += __shfl_xor(v, off);
        if (l == 0){
            float* pB = (mat==1) ? pB_p : pB_n;
            pB[row0 + w] = v;
        }
    }
}

// Nonlinear GELU remainder accumulate (trans path, r3-verified numerics):
// acc += w2h*(|u| - |u|*erfc(|u|/sqrt2)), branchless.
#define GELU_NL_ACC(dnv, cav, accv)                                              \
    {                                                                            \
        const float u  = fmaf(dnv, wk.x, cav + B);                               \
        const float au = fabsf(u);                                               \
        const float tt = __builtin_amdgcn_rcpf(fmaf(0.3326725f, au, 1.0f));      \
        const float P  = fmaf(fmaf(0.7478556f, tt, -0.0958798f), tt, 0.3480242f) * tt; \
        const float e2 = __builtin_amdgcn_exp2f(u * u * -0.72134752044448170f);  \
        accv = fmaf(wk.y, fmaf(-au, P * e2, au), accv);                          \
    }

// K_SD r8: r7 structure (8 rows/block, 4-wave k-split, linear-term fold,
// distributed softmax, REGISTER BATCH-PRELOAD of all inner-loop globals)
// A/B swap: phase-2 gelu back to trans math (r3's GELU_NL_ACC), LUT deleted.
// Discriminates: post-preload, is phase 2 LDS-gather-bound or trans-bound?
__global__ __launch_bounds__(256, 4) void k_sd(
    const float* __restrict__ r_x, const float* __restrict__ rT_p, const float* __restrict__ rT_n,
    const float* __restrict__ A_x, const float* __restrict__ BT_p, const float* __restrict__ BT_n,
    const float* __restrict__ r_p, const float* __restrict__ r_n,
    const float* __restrict__ nx2, const float* __restrict__ np2, const float* __restrict__ nn2,
    const float* __restrict__ pB_p, const float* __restrict__ pB_n,
    const float* __restrict__ s_w1, const float* __restrict__ s_b1,
    const float* __restrict__ s_w2,
    float* __restrict__ psum, float* __restrict__ Spart)
{
    __shared__ float4 xsA[RD];        // 4 KB: x-rep rows 0..3, per r
    __shared__ float4 xsB[RD];        // 4 KB: x-rep rows 4..7
    __shared__ float4 cmA[SH];        // 2 KB: A+b1 rows 0..3
    __shared__ float4 cmB[SH];        // 2 KB: A+b1 rows 4..7
    __shared__ float2 cmW[SH];        // 1 KB: {wn, 0.5*w2}
    __shared__ float  pd[8][4][64];   // 8 KB: [row][kslice][m] partials
    __shared__ float  ny2v[64];
    __shared__ __align__(16) float evb8[64][8];   // 2 KB: per-m ev rows 0..7
    const int t = threadIdx.x;
    const int set = blockIdx.x >> 9;       // 512 blocks per set
    const int rem = blockIdx.x & 511;
    const int n0 = (rem >> 3) << 3;        // 64 octets of 8 rows
    const int mt = rem & 7;
    const int mbase = mt << 6;
    const int tm = t & 63, kh = t >> 6;    // kh in {0..3}, uniform per wave
    const int m = mbase + tm;
    const float* yT = set ? rT_n : rT_p;
    const float* BT = set ? BT_n : BT_p;

    const float pBm = (set ? pB_n : pB_p)[m];   // coalesced per-lane

    xsA[t] = make_float4(r_x[(n0+0)*RD + t], r_x[(n0+1)*RD + t],
                         r_x[(n0+2)*RD + t], r_x[(n0+3)*RD + t]);
    xsB[t] = make_float4(r_x[(n0+4)*RD + t], r_x[(n0+5)*RD + t],
                         r_x[(n0+6)*RD + t], r_x[(n0+7)*RD + t]);
    if (t < SH){
        const float b1v = s_b1[t];
        cmA[t] = make_float4(A_x[(n0+0)*SH + t] + b1v, A_x[(n0+1)*SH + t] + b1v,
                             A_x[(n0+2)*SH + t] + b1v, A_x[(n0+3)*SH + t] + b1v);
        cmB[t] = make_float4(A_x[(n0+4)*SH + t] + b1v, A_x[(n0+5)*SH + t] + b1v,
                             A_x[(n0+6)*SH + t] + b1v, A_x[(n0+7)*SH + t] + b1v);
        cmW[t] = make_float2(s_w1[768*SH + t], 0.5f * s_w2[t]);
    }
    if (t < 64) ny2v[t] = (set ? nn2 : np2)[mbase + t];
    __syncthreads();

    // per-wave linear-term constants:
    // pAk0 = Sum_k w2h*(A[row kh]+b1), pAk1 = same for row kh+4, c0 = Sum_k w2h*wn
    float pAk0, pAk1, c0;
    {
        const float4 aL = cmA[tm], aH = cmA[tm + 64];
        const float4 bL = cmB[tm], bH = cmB[tm + 64];
        const float2 wL = cmW[tm], wH = cmW[tm + 64];
        const float vaL = (kh==0)?aL.x:(kh==1)?aL.y:(kh==2)?aL.z:aL.w;
        const float vaH = (kh==0)?aH.x:(kh==1)?aH.y:(kh==2)?aH.z:aH.w;
        const float vbL = (kh==0)?bL.x:(kh==1)?bL.y:(kh==2)?bL.z:bL.w;
        const float vbH = (kh==0)?bH.x:(kh==1)?bH.y:(kh==2)?bH.z:bH.w;
        float p0 = vaL*wL.y + vaH*wH.y;
        float p1 = vbL*wL.y + vbH*wH.y;
        float cc = wL.x*wL.y + wH.x*wH.y;
        #pragma unroll
        for (int off=32; off>=1; off>>=1){
            p0 += __shfl_xor(p0, off);
            p1 += __shfl_xor(p1, off);
            cc += __shfl_xor(cc, off);
        }
        pAk0 = p0; pAk1 = p1; c0 = cc;
    }

    // phase 1: 8 dots over this wave's r-quarter (64 r), y batch-preloaded
    // in 2 chunks of 32 registers so 32 L2 loads are in flight at once.
    {
        float d0=0.f,d1=0.f,d2=0.f,d3=0.f,d4=0.f,d5=0.f,d6=0.f,d7=0.f;
        const int r0 = kh << 6;
        const float* yp = yT + r0*NN + m;
        #pragma unroll
        for (int ch=0; ch<2; ch++){
            float yv[32];
            #pragma unroll
            for (int rr=0; rr<32; rr++) yv[rr] = yp[(ch*32 + rr)*NN];
            #pragma unroll
            for (int rr=0; rr<32; rr++){
                const float y = yv[rr];
                const float4 xa = xsA[r0 + ch*32 + rr];   // b128 broadcast
                const float4 xb = xsB[r0 + ch*32 + rr];
                d0 = fmaf(xa.x, y, d0); d1 = fmaf(xa.y, y, d1);
                d2 = fmaf(xa.z, y, d2); d3 = fmaf(xa.w, y, d3);
                d4 = fmaf(xb.x, y, d4); d5 = fmaf(xb.y, y, d5);
                d6 = fmaf(xb.z, y, d6); d7 = fmaf(xb.w, y, d7);
            }
        }
        pd[0][kh][tm] = d0; pd[1][kh][tm] = d1;
        pd[2][kh][tm] = d2; pd[3][kh][tm] = d3;
        pd[4][kh][tm] = d4; pd[5][kh][tm] = d5;
        pd[6][kh][tm] = d6; pd[7][kh][tm] = d7;
    }
    __syncthreads();
    float dn0,dn1,dn2,dn3,dn4,dn5,dn6,dn7;
    {
        const float nyc = ny2v[tm];
        const float s0 = pd[0][0][tm]+pd[0][1][tm]+pd[0][2][tm]+pd[0][3][tm];
        const float s1 = pd[1][0][tm]+pd[1][1][tm]+pd[1][2][tm]+pd[1][3][tm];
        const float s2 = pd[2][0][tm]+pd[2][1][tm]+pd[2][2][tm]+pd[2][3][tm];
        const float s3 = pd[3][0][tm]+pd[3][1][tm]+pd[3][2][tm]+pd[3][3][tm];
        const float s4 = pd[4][0][tm]+pd[4][1][tm]+pd[4][2][tm]+pd[4][3][tm];
        const float s5 = pd[5][0][tm]+pd[5][1][tm]+pd[5][2][tm]+pd[5][3][tm];
        const float s6 = pd[6][0][tm]+pd[6][1][tm]+pd[6][2][tm]+pd[6][3][tm];
        const float s7 = pd[7][0][tm]+pd[7][1][tm]+pd[7][2][tm]+pd[7][3][tm];
        dn0 = sqrtf(fmaxf(fmaf(-2.f, s0, nx2[n0+0] + nyc), 0.f));
        dn1 = sqrtf(fmaxf(fmaf(-2.f, s1, nx2[n0+1] + nyc), 0.f));
        dn2 = sqrtf(fmaxf(fmaf(-2.f, s2, nx2[n0+2] + nyc), 0.f));
        dn3 = sqrtf(fmaxf(fmaf(-2.f, s3, nx2[n0+3] + nyc), 0.f));
        dn4 = sqrtf(fmaxf(fmaf(-2.f, s4, nx2[n0+4] + nyc), 0.f));
        dn5 = sqrtf(fmaxf(fmaf(-2.f, s5, nx2[n0+5] + nyc), 0.f));
        dn6 = sqrtf(fmaxf(fmaf(-2.f, s6, nx2[n0+6] + nyc), 0.f));
        dn7 = sqrtf(fmaxf(fmaf(-2.f, s7, nx2[n0+7] + nyc), 0.f));
    }
    __syncthreads();   // pd reads complete before phase-2 overwrites

    // phase 2: trans gelu remainder, this wave's k-quarter (32 k), 8 rows.
    // ALL 32 B values batch-preloaded into registers first (32 loads in
    // flight; loop body is then pure LDS broadcast + VALU/trans).
    float a0=0.f,a1=0.f,a2=0.f,a3=0.f,a4=0.f,a5=0.f,a6=0.f,a7=0.f;
    {
        const float* bp = BT + (kh << 5)*NN + m;
        float Bv[32];
        #pragma unroll
        for (int kk=0; kk<32; kk++) Bv[kk] = bp[kk*NN];
        #pragma unroll
        for (int kk=0; kk<32; kk++){
            const float  B  = Bv[kk];
            const float4 cA = cmA[(kh << 5) + kk];   // b128 broadcast
            const float4 cB = cmB[(kh << 5) + kk];
            const float2 wk = cmW[(kh << 5) + kk];   // b64 broadcast
            GELU_NL_ACC(dn0, cA.x, a0)
            GELU_NL_ACC(dn1, cA.y, a1)
            GELU_NL_ACC(dn2, cA.z, a2)
            GELU_NL_ACC(dn3, cA.w, a3)
            GELU_NL_ACC(dn4, cB.x, a4)
            GELU_NL_ACC(dn5, cB.y, a5)
            GELU_NL_ACC(dn6, cB.z, a6)
            GELU_NL_ACC(dn7, cB.w, a7)
        }
    }
    pd[0][kh][tm] = a0; pd[1][kh][tm] = a1;
    pd[2][kh][tm] = a2; pd[3][kh][tm] = a3;
    pd[4][kh][tm] = a4; pd[5][kh][tm] = a5;
    pd[6][kh][tm] = a6; pd[7][kh][tm] = a7;
    __syncthreads();

    {   // distributed softmax: wave kh handles rows kh and kh+4
        const float L2E = 1.4426950408889634f;
        const float nlL = pd[kh  ][0][tm]+pd[kh  ][1][tm]+pd[kh  ][2][tm]+pd[kh  ][3][tm];
        const float nlH = pd[kh+4][0][tm]+pd[kh+4][1][tm]+pd[kh+4][2][tm]+pd[kh+4][3][tm];
        const float dnL = (kh==0)?dn0:(kh==1)?dn1:(kh==2)?dn2:dn3;
        const float dnH = (kh==0)?dn4:(kh==1)?dn5:(kh==2)?dn6:dn7;
        const float lgL = pAk0 + pBm + dnL*c0 + nlL;
        const float lgH = pAk1 + pBm + dnH*c0 + nlH;
        const float evL = __builtin_amdgcn_exp2f(lgL * L2E);
        const float evH = __builtin_amdgcn_exp2f(lgH * L2E);
        evb8[tm][kh]     = evL;
        evb8[tm][kh + 4] = evH;
        float vL = evL, vH = evH;
        #pragma unroll
        for (int off=32; off>=1; off>>=1){
            vL += __shfl_xor(vL, off);
            vH += __shfl_xor(vH, off);
        }
        if (tm == 0){
            float* Sp = Spart + (set*8 + mt)*NN + n0;
            Sp[kh]     = vL;
            Sp[kh + 4] = vH;
        }
    }
    __syncthreads();

    // fused partial einsum, ry batch-preloaded in 2 chunks of 32 registers.
    {
        const float* ry = (set ? r_n : r_p) + mbase*RD + t;   // coalesced in c=t
        float e0=0.f,e1=0.f,e2=0.f,e3=0.f,e4=0.f,e5=0.f,e6=0.f,e7=0.f;
        #pragma unroll
        for (int ch=0; ch<2; ch++){
            float rv_[32];
            #pragma unroll
            for (int mm=0; mm<32; mm++) rv_[mm] = ry[(ch*32 + mm)*RD];
            #pragma unroll
            for (int mm=0; mm<32; mm++){
                const float rv = rv_[mm];
                const float4 wlo = *(const float4*)&evb8[ch*32 + mm][0];  // b128
                const float4 whi = *(const float4*)&evb8[ch*32 + mm][4];
                e0 = fmaf(wlo.x, rv, e0); e1 = fmaf(wlo.y, rv, e1);
                e2 = fmaf(wlo.z, rv, e2); e3 = fmaf(wlo.w, rv, e3);
                e4 = fmaf(whi.x, rv, e4); e5 = fmaf(whi.y, rv, e5);
                e6 = fmaf(whi.z, rv, e6); e7 = fmaf(whi.w, rv, e7);
            }
        }
        float* P = psum + ((set*8 + mt)*NN + n0)*RD;
        P[t]        = e0;
        P[RD + t]   = e1;
        P[2*RD + t] = e2;
        P[3*RD + t] = e3;
        P[4*RD + t] = e4;
        P[5*RD + t] = e5;
        P[6*RD + t] = e6;
        P[7*RD + t] = e7;
    }
}

// K_FIN: dv = Sum_mt psum_p/Sp - Sum_mt psum_n/Sn (8 mt slices); out = dv @ out_w.
// 1024 blocks (256 n-pairs x 4 col-tiles) x 256 thr = 4/CU, 16 waves/CU.
__global__ __launch_bounds__(256) void k_fin(
    const float* __restrict__ psum, const float* __restrict__ Spart,
    const float* __restrict__ out_w, float* __restrict__ out)
{
    __shared__ float dv[2][RD];   // 2 KB
    const int t = threadIdx.x;
    const int np = blockIdx.x >> 2, ct = blockIdx.x & 3;
    const int n0 = np << 1;
    const int cb = ct << 7;

    #pragma unroll
    for (int rep=0; rep<2; rep++){   // dv: 512 entries, 2/thread
        const int idx = rep*256 + t;
        const int j = idx >> 8, c = idx & 255;
        const int n = n0 + j;
        float Sp = 0.f, Sn = 0.f;
        #pragma unroll
        for (int q=0;q<8;q++){
            Sp += Spart[q*NN + n];
            Sn += Spart[(8+q)*NN + n];
        }
        float vp = 0.f, vn = 0.f;
        #pragma unroll
        for (int q=0;q<8;q++){
            vp += psum[(q*NN + n)*RD + c];
            vn += psum[((8+q)*NN + n)*RD + c];
        }
        dv[j][c] = vp * (1.0f/Sp) - vn * (1.0f/Sn);
    }
    __syncthreads();

    {   // out[j][cb+cc] = Sum_r dv[j][r]*out_w[r][cb+cc]
        const int j = t >> 7, cc = t & 127;
        const int col = cb + cc;
        float o = 0.f;
        const float* wo = out_w + col;
        #pragma unroll 8
        for (int r=0; r<RD; r++){ o = fmaf(dv[j][r], *wo, o); wo += IN; }
        out[(n0+j)*IN + col] = o;
    }
}

extern "C" void kernel_launch(void* const* d_in, const int* in_sizes, int n_in,
                              void* d_out, int out_size, void* d_ws, size_t ws_size,
                              hipStream_t stream)
{
    const float* fx  = (const float*)d_in[0];
    const float* fp  = (const float*)d_in[1];
    const float* fn  = (const float*)d_in[2];
    const float* gw1 = (const float*)d_in[3];
    const float* gb1 = (const float*)d_in[4];
    const float* gw2 = (const float*)d_in[5];
    const float* gb2 = (const float*)d_in[6];
    const float* ow  = (const float*)d_in[7];
    const float* sw1 = (const float*)d_in[8];
    const float* sb1 = (const float*)d_in[9];
    const float* sw2 = (const float*)d_in[10];
    float* out = (float*)d_out;

    float* ws   = (float*)d_ws;
    float* r_x  = ws;               // 512*256 row-major
    float* r_p  = r_x  + 131072;
    float* r_n  = r_p  + 131072;
    float* rT_p = r_n  + 131072;    // 256*512 column-major
    float* rT_n = rT_p + 131072;
    float* A_x  = rT_n + 131072;    // 512*128 row-major [n][k]
    float* BT_p = A_x  + 65536;     // 128*512 column-major [k][m]
    float* BT_n = BT_p + 65536;
    float* Spar = BT_n + 65536;     // 2*8*512
    float* nx2  = Spar + 8192;      // 512
    float* np2  = nx2  + 512;
    float* nn2  = np2  + 512;
    float* pB_p = nn2  + 512;       // 512: Sum_k w2h*B (pos)
    float* pB_n = pB_p + 512;       // 512: Sum_k w2h*B (neg)
    float* psum = pB_n + 512;       // 2*8*512*256 (8 MB)

    hipLaunchKernelGGL(k_rep, dim3(384), dim3(512), 0, stream,
                       fx, fp, fn, gw1, gb1, gw2, gb2, sw1, sw2,
                       r_x, r_p, r_n, rT_p, rT_n, A_x, BT_p, BT_n,
                       nx2, np2, nn2, pB_p, pB_n);
    hipLaunchKernelGGL(k_sd, dim3(1024), dim3(256), 0, stream,
                       r_x, rT_p, rT_n, A_x, BT_p, BT_n, r_p, r_n,
                       nx2, np2, nn2, pB_p, pB_n, sw1, sb1, sw2, psum, Spar);
    hipLaunchKernelGGL(k_fin, dim3(1024), dim3(256), 0, stream,
                       psum, Spar, ow, out);
}

// Round 10
// 144.191 us; speedup vs baseline: 1.0727x; 1.0727x over previous
//
#include <hip/hip_runtime.h>
#include <math.h>

#define NN 512   // set size / rows of feat_x
#define IN 512   // INPUT_DIM
#define HD 256   // HIDDEN_DIM
#define RD 256   // REP_DIM
#define SH 128   // SCORE_HIDDEN

// Branchless erf-GELU, A&S 7.1.26 (5-term) -- g-MLP hidden layer + LUT build.
__device__ __forceinline__ float gelu_fast(float x){
    const float z  = x * 0.70710678118654752f;
    const float az = fabsf(z);
    const float t  = __builtin_amdgcn_rcpf(fmaf(0.3275911f, az, 1.0f));
    float p = fmaf(1.061405429f, t, -1.453152027f);
    p = fmaf(p, t, 1.421413741f);
    p = fmaf(p, t, -0.284496736f);
    p = fmaf(p, t, 0.254829592f);
    p = p * t;
    const float e = __builtin_amdgcn_exp2f(z * z * -1.4426950408889634f);
    const float E = p * e;                        // erfc(|z|)
    const float one_plus_erf = (x >= 0.0f) ? (2.0f - E) : E;
    return 0.5f * x * one_plus_erf;
}

// K_REP: fused g-MLP + score-net projections + row norms (r15/r16 winner)
// + per-m score-linear partial pB[m] = Sum_k 0.5*s_w2[k]*B[k][m].
__global__ __launch_bounds__(512) void k_rep(
    const float* __restrict__ fx, const float* __restrict__ fp, const float* __restrict__ fn,
    const float* __restrict__ w1, const float* __restrict__ b1,
    const float* __restrict__ w2, const float* __restrict__ b2,
    const float* __restrict__ s_w1, const float* __restrict__ s_w2,
    float* __restrict__ r_x, float* __restrict__ r_p, float* __restrict__ r_n,
    float* __restrict__ rT_p, float* __restrict__ rT_n,
    float* __restrict__ A_x, float* __restrict__ BT_p, float* __restrict__ BT_n,
    float* __restrict__ nx2, float* __restrict__ np2, float* __restrict__ nn2,
    float* __restrict__ pB_p, float* __restrict__ pB_n)
{
    __shared__ float xs[4][IN];        // 8 KB
    __shared__ float ps[8][4][HD];     // 32 KB partials (reused by all GEMM phases)
    __shared__ float hs[4][HD];        // 4 KB
    __shared__ float rloc[4][RD];      // 4 KB
    __shared__ float ab4[4][SH];       // 2 KB
    const int t = threadIdx.x;
    const int mat = blockIdx.x >> 7;
    const int row0 = (blockIdx.x & 127) << 2;
    const float* src = (mat==0) ? fx : (mat==1) ? fp : fn;

    {   // stage 4 feat rows: 512 float4s
        const int j = t >> 7, c4 = (t & 127) << 2;
        *(float4*)&xs[j][c4] = *(const float4*)&src[(row0+j)*IN + c4];
    }
    __syncthreads();

    const int cg = t & 63, s = t >> 6;   // 64 colgroups x 8 K-slices
    const int c0 = cg << 2;

    {   // GEMM1: K=512, slice [s*64, s*64+64)
        float4 acc[4];
        #pragma unroll
        for (int j=0;j<4;j++) acc[j] = make_float4(0.f,0.f,0.f,0.f);
        const float* wp = w1 + (s*64)*HD + c0;
        #pragma unroll 8
        for (int ii=0; ii<64; ii++){
            float4 w = *(const float4*)wp; wp += HD;
            const int i = s*64 + ii;
            #pragma unroll
            for (int j=0;j<4;j++){
                const float xv = xs[j][i];
                acc[j].x = fmaf(xv, w.x, acc[j].x);
                acc[j].y = fmaf(xv, w.y, acc[j].y);
                acc[j].z = fmaf(xv, w.z, acc[j].z);
                acc[j].w = fmaf(xv, w.w, acc[j].w);
            }
        }
        #pragma unroll
        for (int j=0;j<4;j++) *(float4*)&ps[s][j][c0] = acc[j];
    }
    __syncthreads();

    #pragma unroll
    for (int rep=0; rep<2; rep++){   // reduce + bias + GELU -> hs
        const int idx = rep*512 + t;
        const int j = idx >> 8, c = idx & 255;
        float v = b1[c];
        #pragma unroll
        for (int ss=0; ss<8; ss++) v += ps[ss][j][c];
        hs[j][c] = gelu_fast(v);
    }
    __syncthreads();

    {   // GEMM2: K=256, slice [s*32, s*32+32)
        float4 acc[4];
        #pragma unroll
        for (int j=0;j<4;j++) acc[j] = make_float4(0.f,0.f,0.f,0.f);
        const float* wp = w2 + (s*32)*RD + c0;
        #pragma unroll 8
        for (int ii=0; ii<32; ii++){
            float4 w = *(const float4*)wp; wp += RD;
            const int i = s*32 + ii;
            #pragma unroll
            for (int j=0;j<4;j++){
                const float xv = hs[j][i];
                acc[j].x = fmaf(xv, w.x, acc[j].x);
                acc[j].y = fmaf(xv, w.y, acc[j].y);
                acc[j].z = fmaf(xv, w.z, acc[j].z);
                acc[j].w = fmaf(xv, w.w, acc[j].w);
            }
        }
        #pragma unroll
        for (int j=0;j<4;j++) *(float4*)&ps[s][j][c0] = acc[j];
    }
    __syncthreads();

    float* rout = (mat==0) ? r_x : (mat==1) ? r_p : r_n;
    #pragma unroll
    for (int rep=0; rep<2; rep++){   // reduce + bias -> rloc + global r
        const int idx = rep*512 + t;
        const int j = idx >> 8, c = idx & 255;
        float v = b2[c];
        #pragma unroll
        for (int ss=0; ss<8; ss++) v += ps[ss][j][c];
        rloc[j][c] = v;
        rout[(row0+j)*RD + c] = v;
    }
    __syncthreads();   // rloc complete; ps free for reuse

    if (t < 256){   // squared row norms: waves 0..3 -> rows 0..3
        const int w = t >> 6, l = t & 63;
        float v = 0.f;
        #pragma unroll
        for (int q=0;q<4;q++){ const float e = rloc[w][l + 64*q]; v = fmaf(e,e,v); }
        #pragma unroll
        for (int off=32; off>=1; off>>=1) v += __shfl_xor(v, off);
        if (l==0){
            float* nrm = (mat==0) ? nx2 : (mat==1) ? np2 : nn2;
            nrm[row0 + w] = v;
        }
    }
    if (mat && t < 256){   // transposed rep copy rT[r][m], float4 across rows
        float* rT = (mat==1) ? rT_p : rT_n;
        float4 q = make_float4(rloc[0][t], rloc[1][t], rloc[2][t], rloc[3][t]);
        *(float4*)&rT[t*NN + row0] = q;
    }

    {   // score-net projection: 128 cols, K=256 in 16 slices of 16
        const int cg2 = t & 31, s2 = t >> 5;
        const int cc0 = cg2 << 2;
        const float sgn = (mat==0) ? -1.0f : 1.0f;
        const int base1 = (mat==0) ? 0 : 256;
        const float* p1 = s_w1 + (base1 + s2*16)*SH + cc0;
        const float* p3 = s_w1 + (512   + s2*16)*SH + cc0;
        float4 a[4];
        #pragma unroll
        for (int j=0;j<4;j++) a[j] = make_float4(0.f,0.f,0.f,0.f);
        #pragma unroll 8
        for (int ii=0; ii<16; ii++){
            float4 wa = *(const float4*)p1; p1 += SH;
            float4 wd = *(const float4*)p3; p3 += SH;
            float4 w;
            w.x = fmaf(sgn, wd.x, wa.x);
            w.y = fmaf(sgn, wd.y, wa.y);
            w.z = fmaf(sgn, wd.z, wa.z);
            w.w = fmaf(sgn, wd.w, wa.w);
            const int i = s2*16 + ii;
            #pragma unroll
            for (int j=0;j<4;j++){
                const float xv = rloc[j][i];
                a[j].x = fmaf(xv, w.x, a[j].x);
                a[j].y = fmaf(xv, w.y, a[j].y);
                a[j].z = fmaf(xv, w.z, a[j].z);
                a[j].w = fmaf(xv, w.w, a[j].w);
            }
        }
        float* psf = &ps[0][0][0];   // reuse as [16][4][128]
        #pragma unroll
        for (int j=0;j<4;j++) *(float4*)&psf[(s2*4 + j)*SH + cc0] = a[j];
    }
    __syncthreads();

    {   // reduce 16 slices: 4 rows x 128 cols = 512 outputs
        const float* psf = &ps[0][0][0];
        const int j = t >> 7, c = t & 127;
        float v = 0.f;
        #pragma unroll
        for (int ss=0; ss<16; ss++) v += psf[(ss*4 + j)*SH + c];
        if (mat==0) A_x[(row0+j)*SH + c] = v;
        else        ab4[j][c] = v;
    }
    __syncthreads();
    if (mat && t < 128){   // BT[k][m], float4 across rows
        float* BT = (mat==1) ? BT_p : BT_n;
        float4 q = make_float4(ab4[0][t], ab4[1][t], ab4[2][t], ab4[3][t]);
        *(float4*)&BT[t*NN + row0] = q;
    }
    if (mat && t < 256){   // pB[m] = Sum_k (0.5*s_w2[k]) * B[k][m], wave w -> row w
        const int w = t >> 6, l = t & 63;
        const float w2a = 0.5f * s_w2[l];
        const float w2b = 0.5f * s_w2[l + 64];
        float v = ab4[w][l]*w2a + ab4[w][l+64]*w2b;
        #pragma unroll
        for (int off=32; off>=1; off>>=1) v += __shfl_xor(v, off);
        if (l == 0){
            float* pB = (mat==1) ? pB_p : pB_n;
            pB[row0 + w] = v;
        }
    }
}

// LUT gelu remainder: N(u) = u*erf(u/sqrt2), tabled over u in [-16,16],
// 1024 entries (val, delta-to-next), linear interp in INDEX units.
#define GELU_LUT_ACC(dnv, cav, accv)                                             \
    {                                                                            \
        const float u  = fmaf(dnv, wk.x, cav + B);                               \
        const float xq = fminf(fmaxf(fmaf(u, 32.f, 512.f), 0.f), 1022.999f);     \
        const float fi = floorf(xq);                                             \
        const float2 e = lut[(int)fi];                                           \
        accv = fmaf(wk.y, fmaf(xq - fi, e.y, e.x), accv);                        \
    }

// K_SD r9: r7 keeper (LUT + register batch-preload; r8 A/B proved trans
// regresses 6us) + cross-barrier load hoisting: __syncthreads is a full
// fence so hipcc cannot hoist globals past it -- do it manually. Bv issued
// before the dn-combine (in flight across 16 LDS reads + 8 sqrt + barrier);
// einsum's first ry chunk issued before the softmax section (in flight
// across exp2 + 12 shfl + barrier).
__global__ __launch_bounds__(256, 4) void k_sd(
    const float* __restrict__ r_x, const float* __restrict__ rT_p, const float* __restrict__ rT_n,
    const float* __restrict__ A_x, const float* __restrict__ BT_p, const float* __restrict__ BT_n,
    const float* __restrict__ r_p, const float* __restrict__ r_n,
    const float* __restrict__ nx2, const float* __restrict__ np2, const float* __restrict__ nn2,
    const float* __restrict__ pB_p, const float* __restrict__ pB_n,
    const float* __restrict__ s_w1, const float* __restrict__ s_b1,
    const float* __restrict__ s_w2,
    float* __restrict__ psum, float* __restrict__ Spart)
{
    __shared__ float4 xsA[RD];        // 4 KB: x-rep rows 0..3, per r
    __shared__ float4 xsB[RD];        // 4 KB: x-rep rows 4..7
    __shared__ float4 cmA[SH];        // 2 KB: A+b1 rows 0..3
    __shared__ float4 cmB[SH];        // 2 KB: A+b1 rows 4..7
    __shared__ float2 cmW[SH];        // 1 KB: {wn, 0.5*w2}
    __shared__ float  pd[8][4][64];   // 8 KB: [row][kslice][m] partials
    __shared__ float  ny2v[64];
    __shared__ __align__(16) float evb8[64][8];   // 2 KB: per-m ev rows 0..7
    __shared__ float2 lut[1024];      // 8 KB: N(u) value + delta table
    const int t = threadIdx.x;
    const int set = blockIdx.x >> 9;       // 512 blocks per set
    const int rem = blockIdx.x & 511;
    const int n0 = (rem >> 3) << 3;        // 64 octets of 8 rows
    const int mt = rem & 7;
    const int mbase = mt << 6;
    const int tm = t & 63, kh = t >> 6;    // kh in {0..3}, uniform per wave
    const int m = mbase + tm;
    const float* yT = set ? rT_n : rT_p;
    const float* BT = set ? BT_n : BT_p;
    const float* ry = (set ? r_n : r_p) + mbase*RD + t;   // einsum src, coalesced

    const float pBm = (set ? pB_n : pB_p)[m];   // coalesced per-lane

    {   // build LUT: 4 entries/thread, coalesced
        #pragma unroll
        for (int j=0;j<4;j++){
            const int i = t + j*256;
            const float u0 = (float)(i - 512) * 0.03125f;
            const float u1 = u0 + 0.03125f;
            const float f0 = 2.f*gelu_fast(u0) - u0;   // u*erf(u/sqrt2)
            const float f1 = 2.f*gelu_fast(u1) - u1;
            lut[i] = make_float2(f0, f1 - f0);         // delta per index step
        }
    }

    xsA[t] = make_float4(r_x[(n0+0)*RD + t], r_x[(n0+1)*RD + t],
                         r_x[(n0+2)*RD + t], r_x[(n0+3)*RD + t]);
    xsB[t] = make_float4(r_x[(n0+4)*RD + t], r_x[(n0+5)*RD + t],
                         r_x[(n0+6)*RD + t], r_x[(n0+7)*RD + t]);
    if (t < SH){
        const float b1v = s_b1[t];
        cmA[t] = make_float4(A_x[(n0+0)*SH + t] + b1v, A_x[(n0+1)*SH + t] + b1v,
                             A_x[(n0+2)*SH + t] + b1v, A_x[(n0+3)*SH + t] + b1v);
        cmB[t] = make_float4(A_x[(n0+4)*SH + t] + b1v, A_x[(n0+5)*SH + t] + b1v,
                             A_x[(n0+6)*SH + t] + b1v, A_x[(n0+7)*SH + t] + b1v);
        cmW[t] = make_float2(s_w1[768*SH + t], 0.5f * s_w2[t]);
    }
    if (t < 64) ny2v[t] = (set ? nn2 : np2)[mbase + t];
    __syncthreads();

    // per-wave linear-term constants:
    // pAk0 = Sum_k w2h*(A[row kh]+b1), pAk1 = same for row kh+4, c0 = Sum_k w2h*wn
    float pAk0, pAk1, c0;
    {
        const float4 aL = cmA[tm], aH = cmA[tm + 64];
        const float4 bL = cmB[tm], bH = cmB[tm + 64];
        const float2 wL = cmW[tm], wH = cmW[tm + 64];
        const float vaL = (kh==0)?aL.x:(kh==1)?aL.y:(kh==2)?aL.z:aL.w;
        const float vaH = (kh==0)?aH.x:(kh==1)?aH.y:(kh==2)?aH.z:aH.w;
        const float vbL = (kh==0)?bL.x:(kh==1)?bL.y:(kh==2)?bL.z:bL.w;
        const float vbH = (kh==0)?bH.x:(kh==1)?bH.y:(kh==2)?bH.z:bH.w;
        float p0 = vaL*wL.y + vaH*wH.y;
        float p1 = vbL*wL.y + vbH*wH.y;
        float cc = wL.x*wL.y + wH.x*wH.y;
        #pragma unroll
        for (int off=32; off>=1; off>>=1){
            p0 += __shfl_xor(p0, off);
            p1 += __shfl_xor(p1, off);
            cc += __shfl_xor(cc, off);
        }
        pAk0 = p0; pAk1 = p1; c0 = cc;
    }

    // phase 1: 8 dots over this wave's r-quarter (64 r), y batch-preloaded
    // in 2 chunks of 32 registers so 32 L2 loads are in flight at once.
    {
        float d0=0.f,d1=0.f,d2=0.f,d3=0.f,d4=0.f,d5=0.f,d6=0.f,d7=0.f;
        const int r0 = kh << 6;
        const float* yp = yT + r0*NN + m;
        #pragma unroll
        for (int ch=0; ch<2; ch++){
            float yv[32];
            #pragma unroll
            for (int rr=0; rr<32; rr++) yv[rr] = yp[(ch*32 + rr)*NN];
            #pragma unroll
            for (int rr=0; rr<32; rr++){
                const float y = yv[rr];
                const float4 xa = xsA[r0 + ch*32 + rr];   // b128 broadcast
                const float4 xb = xsB[r0 + ch*32 + rr];
                d0 = fmaf(xa.x, y, d0); d1 = fmaf(xa.y, y, d1);
                d2 = fmaf(xa.z, y, d2); d3 = fmaf(xa.w, y, d3);
                d4 = fmaf(xb.x, y, d4); d5 = fmaf(xb.y, y, d5);
                d6 = fmaf(xb.z, y, d6); d7 = fmaf(xb.w, y, d7);
            }
        }
        pd[0][kh][tm] = d0; pd[1][kh][tm] = d1;
        pd[2][kh][tm] = d2; pd[3][kh][tm] = d3;
        pd[4][kh][tm] = d4; pd[5][kh][tm] = d5;
        pd[6][kh][tm] = d6; pd[7][kh][tm] = d7;
    }

    // HOIST: phase-2 B preload issued here -- independent of pd/dn, its
    // ~300cy L2 latency hides under the barrier + dn-combine below.
    float Bv[32];
    {
        const float* bp = BT + (kh << 5)*NN + m;
        #pragma unroll
        for (int kk=0; kk<32; kk++) Bv[kk] = bp[kk*NN];
    }
    __syncthreads();
    float dn0,dn1,dn2,dn3,dn4,dn5,dn6,dn7;
    {
        const float nyc = ny2v[tm];
        const float s0 = pd[0][0][tm]+pd[0][1][tm]+pd[0][2][tm]+pd[0][3][tm];
        const float s1 = pd[1][0][tm]+pd[1][1][tm]+pd[1][2][tm]+pd[1][3][tm];
        const float s2 = pd[2][0][tm]+pd[2][1][tm]+pd[2][2][tm]+pd[2][3][tm];
        const float s3 = pd[3][0][tm]+pd[3][1][tm]+pd[3][2][tm]+pd[3][3][tm];
        const float s4 = pd[4][0][tm]+pd[4][1][tm]+pd[4][2][tm]+pd[4][3][tm];
        const float s5 = pd[5][0][tm]+pd[5][1][tm]+pd[5][2][tm]+pd[5][3][tm];
        const float s6 = pd[6][0][tm]+pd[6][1][tm]+pd[6][2][tm]+pd[6][3][tm];
        const float s7 = pd[7][0][tm]+pd[7][1][tm]+pd[7][2][tm]+pd[7][3][tm];
        dn0 = sqrtf(fmaxf(fmaf(-2.f, s0, nx2[n0+0] + nyc), 0.f));
        dn1 = sqrtf(fmaxf(fmaf(-2.f, s1, nx2[n0+1] + nyc), 0.f));
        dn2 = sqrtf(fmaxf(fmaf(-2.f, s2, nx2[n0+2] + nyc), 0.f));
        dn3 = sqrtf(fmaxf(fmaf(-2.f, s3, nx2[n0+3] + nyc), 0.f));
        dn4 = sqrtf(fmaxf(fmaf(-2.f, s4, nx2[n0+4] + nyc), 0.f));
        dn5 = sqrtf(fmaxf(fmaf(-2.f, s5, nx2[n0+5] + nyc), 0.f));
        dn6 = sqrtf(fmaxf(fmaf(-2.f, s6, nx2[n0+6] + nyc), 0.f));
        dn7 = sqrtf(fmaxf(fmaf(-2.f, s7, nx2[n0+7] + nyc), 0.f));
    }
    __syncthreads();   // pd reads complete before phase-2 overwrites

    // phase 2: LUT gelu remainder, this wave's k-quarter (32 k), 8 rows.
    // B already resident in registers (hoisted above).
    float a0=0.f,a1=0.f,a2=0.f,a3=0.f,a4=0.f,a5=0.f,a6=0.f,a7=0.f;
    {
        #pragma unroll
        for (int kk=0; kk<32; kk++){
            const float  B  = Bv[kk];
            const float4 cA = cmA[(kh << 5) + kk];   // b128 broadcast
            const float4 cB = cmB[(kh << 5) + kk];
            const float2 wk = cmW[(kh << 5) + kk];   // b64 broadcast
            GELU_LUT_ACC(dn0, cA.x, a0)
            GELU_LUT_ACC(dn1, cA.y, a1)
            GELU_LUT_ACC(dn2, cA.z, a2)
            GELU_LUT_ACC(dn3, cA.w, a3)
            GELU_LUT_ACC(dn4, cB.x, a4)
            GELU_LUT_ACC(dn5, cB.y, a5)
            GELU_LUT_ACC(dn6, cB.z, a6)
            GELU_LUT_ACC(dn7, cB.w, a7)
        }
    }
    pd[0][kh][tm] = a0; pd[1][kh][tm] = a1;
    pd[2][kh][tm] = a2; pd[3][kh][tm] = a3;
    pd[4][kh][tm] = a4; pd[5][kh][tm] = a5;
    pd[6][kh][tm] = a6; pd[7][kh][tm] = a7;

    // HOIST: einsum's first ry chunk issued here -- independent of the
    // softmax below, hides under exp2 + shfl reduce + 2 barriers.
    float rv0_[32];
    {
        #pragma unroll
        for (int mm=0; mm<32; mm++) rv0_[mm] = ry[mm*RD];
    }
    __syncthreads();

    {   // distributed softmax: wave kh handles rows kh and kh+4
        const float L2E = 1.4426950408889634f;
        const float nlL = pd[kh  ][0][tm]+pd[kh  ][1][tm]+pd[kh  ][2][tm]+pd[kh  ][3][tm];
        const float nlH = pd[kh+4][0][tm]+pd[kh+4][1][tm]+pd[kh+4][2][tm]+pd[kh+4][3][tm];
        const float dnL = (kh==0)?dn0:(kh==1)?dn1:(kh==2)?dn2:dn3;
        const float dnH = (kh==0)?dn4:(kh==1)?dn5:(kh==2)?dn6:dn7;
        const float lgL = pAk0 + pBm + dnL*c0 + nlL;
        const float lgH = pAk1 + pBm + dnH*c0 + nlH;
        const float evL = __builtin_amdgcn_exp2f(lgL * L2E);
        const float evH = __builtin_amdgcn_exp2f(lgH * L2E);
        evb8[tm][kh]     = evL;
        evb8[tm][kh + 4] = evH;
        float vL = evL, vH = evH;
        #pragma unroll
        for (int off=32; off>=1; off>>=1){
            vL += __shfl_xor(vL, off);
            vH += __shfl_xor(vH, off);
        }
        if (tm == 0){
            float* Sp = Spart + (set*8 + mt)*NN + n0;
            Sp[kh]     = vL;
            Sp[kh + 4] = vH;
        }
    }
    __syncthreads();

    // fused partial einsum: chunk 0 from hoisted registers, chunk 1 inline.
    {
        float e0=0.f,e1=0.f,e2=0.f,e3=0.f,e4=0.f,e5=0.f,e6=0.f,e7=0.f;
        #pragma unroll
        for (int mm=0; mm<32; mm++){
            const float rv = rv0_[mm];
            const float4 wlo = *(const float4*)&evb8[mm][0];  // b128
            const float4 whi = *(const float4*)&evb8[mm][4];
            e0 = fmaf(wlo.x, rv, e0); e1 = fmaf(wlo.y, rv, e1);
            e2 = fmaf(wlo.z, rv, e2); e3 = fmaf(wlo.w, rv, e3);
            e4 = fmaf(whi.x, rv, e4); e5 = fmaf(whi.y, rv, e5);
            e6 = fmaf(whi.z, rv, e6); e7 = fmaf(whi.w, rv, e7);
        }
        {
            float rv1_[32];
            #pragma unroll
            for (int mm=0; mm<32; mm++) rv1_[mm] = ry[(32 + mm)*RD];
            #pragma unroll
            for (int mm=0; mm<32; mm++){
                const float rv = rv1_[mm];
                const float4 wlo = *(const float4*)&evb8[32 + mm][0];
                const float4 whi = *(const float4*)&evb8[32 + mm][4];
                e0 = fmaf(wlo.x, rv, e0); e1 = fmaf(wlo.y, rv, e1);
                e2 = fmaf(wlo.z, rv, e2); e3 = fmaf(wlo.w, rv, e3);
                e4 = fmaf(whi.x, rv, e4); e5 = fmaf(whi.y, rv, e5);
                e6 = fmaf(whi.z, rv, e6); e7 = fmaf(whi.w, rv, e7);
            }
        }
        float* P = psum + ((set*8 + mt)*NN + n0)*RD;
        P[t]        = e0;
        P[RD + t]   = e1;
        P[2*RD + t] = e2;
        P[3*RD + t] = e3;
        P[4*RD + t] = e4;
        P[5*RD + t] = e5;
        P[6*RD + t] = e6;
        P[7*RD + t] = e7;
    }
}

// K_FIN: dv = Sum_mt psum_p/Sp - Sum_mt psum_n/Sn (8 mt slices); out = dv @ out_w.
// 1024 blocks (256 n-pairs x 4 col-tiles) x 256 thr = 4/CU, 16 waves/CU.
__global__ __launch_bounds__(256) void k_fin(
    const float* __restrict__ psum, const float* __restrict__ Spart,
    const float* __restrict__ out_w, float* __restrict__ out)
{
    __shared__ float dv[2][RD];   // 2 KB
    const int t = threadIdx.x;
    const int np = blockIdx.x >> 2, ct = blockIdx.x & 3;
    const int n0 = np << 1;
    const int cb = ct << 7;

    #pragma unroll
    for (int rep=0; rep<2; rep++){   // dv: 512 entries, 2/thread
        const int idx = rep*256 + t;
        const int j = idx >> 8, c = idx & 255;
        const int n = n0 + j;
        float Sp = 0.f, Sn = 0.f;
        #pragma unroll
        for (int q=0;q<8;q++){
            Sp += Spart[q*NN + n];
            Sn += Spart[(8+q)*NN + n];
        }
        float vp = 0.f, vn = 0.f;
        #pragma unroll
        for (int q=0;q<8;q++){
            vp += psum[(q*NN + n)*RD + c];
            vn += psum[((8+q)*NN + n)*RD + c];
        }
        dv[j][c] = vp * (1.0f/Sp) - vn * (1.0f/Sn);
    }
    __syncthreads();

    {   // out[j][cb+cc] = Sum_r dv[j][r]*out_w[r][cb+cc]
        const int j = t >> 7, cc = t & 127;
        const int col = cb + cc;
        float o = 0.f;
        const float* wo = out_w + col;
        #pragma unroll 8
        for (int r=0; r<RD; r++){ o = fmaf(dv[j][r], *wo, o); wo += IN; }
        out[(n0+j)*IN + col] = o;
    }
}

extern "C" void kernel_launch(void* const* d_in, const int* in_sizes, int n_in,
                              void* d_out, int out_size, void* d_ws, size_t ws_size,
                              hipStream_t stream)
{
    const float* fx  = (const float*)d_in[0];
    const float* fp  = (const float*)d_in[1];
    const float* fn  = (const float*)d_in[2];
    const float* gw1 = (const float*)d_in[3];
    const float* gb1 = (const float*)d_in[4];
    const float* gw2 = (const float*)d_in[5];
    const float* gb2 = (const float*)d_in[6];
    const float* ow  = (const float*)d_in[7];
    const float* sw1 = (const float*)d_in[8];
    const float* sb1 = (const float*)d_in[9];
    const float* sw2 = (const float*)d_in[10];
    float* out = (float*)d_out;

    float* ws   = (float*)d_ws;
    float* r_x  = ws;               // 512*256 row-major
    float* r_p  = r_x  + 131072;
    float* r_n  = r_p  + 131072;
    float* rT_p = r_n  + 131072;    // 256*512 column-major
    float* rT_n = rT_p + 131072;
    float* A_x  = rT_n + 131072;    // 512*128 row-major [n][k]
    float* BT_p = A_x  + 65536;     // 128*512 column-major [k][m]
    float* BT_n = BT_p + 65536;
    float* Spar = BT_n + 65536;     // 2*8*512
    float* nx2  = Spar + 8192;      // 512
    float* np2  = nx2  + 512;
    float* nn2  = np2  + 512;
    float* pB_p = nn2  + 512;       // 512: Sum_k w2h*B (pos)
    float* pB_n = pB_p + 512;       // 512: Sum_k w2h*B (neg)
    float* psum = pB_n + 512;       // 2*8*512*256 (8 MB)

    hipLaunchKernelGGL(k_rep, dim3(384), dim3(512), 0, stream,
                       fx, fp, fn, gw1, gb1, gw2, gb2, sw1, sw2,
                       r_x, r_p, r_n, rT_p, rT_n, A_x, BT_p, BT_n,
                       nx2, np2, nn2, pB_p, pB_n);
    hipLaunchKernelGGL(k_sd, dim3(1024), dim3(256), 0, stream,
                       r_x, rT_p, rT_n, A_x, BT_p, BT_n, r_p, r_n,
                       nx2, np2, nn2, pB_p, pB_n, sw1, sb1, sw2, psum, Spar);
    hipLaunchKernelGGL(k_fin, dim3(1024), dim3(256), 0, stream,
                       psum, Spar, ow, out);
}